// Round 4
// baseline (48.478 us; speedup 1.0000x reference)
//
#include <hip/hip_runtime.h>
#include <math.h>

#define CIN  32
#define COUT 32
#define BB   4
#define HH   80
#define WW   80
#define HW   (HH * WW)
#define TH   16                 // output rows per block
#define CW   40                 // output cols per block
#define XR   (TH + 4)           // 20 haloed rows
#define XC   (CW + 4)           // 44 haloed cols
#define TILE (XR * XC)          // 880 floats
#define NTHREADS 320            // 16 rows x 20 groups of 2 cols

__global__ __launch_bounds__(NTHREADS, 6) void semiconv_kernel(
    const float* __restrict__ x,     // [B, CIN, H, W]
    const float* __restrict__ w,     // [COUT, CIN, 5, 5]
    const float* __restrict__ bias,  // [COUT]
    float* __restrict__ out)         // [B, COUT, H, W]
{
    __shared__ __align__(16) float xs[2][TILE];

    const int tid = threadIdx.x;
    const int bh  = blockIdx.x >> 1;          // 0..4 row stripe
    const int chf = blockIdx.x & 1;           // 0..1 col half
    const int co  = blockIdx.y;               // 0..31
    const int b   = blockIdx.z;               // 0..3
    const int h0  = bh * TH;
    const int w0  = chf * CW;

    const int ty = tid / 20;                  // 0..15
    const int tx = tid % 20;                  // 0..19
    const int wc = tx * 2;                    // first of 2 output cols

    // staging offsets (same for every ci): 2 guaranteed + 1 conditional
    int goff[3], lidx[3];
    #pragma unroll
    for (int i = 0; i < 3; ++i) {
        int idx = tid + i * NTHREADS;
        int r = idx / XC, c = idx % XC;
        int gr = h0 + r - 2, gc = w0 + c - 2;
        lidx[i] = idx;
        goff[i] = (gr >= 0 && gr < HH && gc >= 0 && gc < WW) ? (gr * WW + gc) : -1;
    }
    const bool has3 = (tid < TILE - 2 * NTHREADS);   // tid < 240

    float pre[3];
    auto prefetch = [&](int ci) {
        const float* xp = x + (size_t)(b * CIN + ci) * HW;
        pre[0] = (goff[0] >= 0) ? xp[goff[0]] : -INFINITY;
        pre[1] = (goff[1] >= 0) ? xp[goff[1]] : -INFINITY;
        if (has3) pre[2] = (goff[2] >= 0) ? xp[goff[2]] : -INFINITY;
    };

    const float* wbase = w + (size_t)(co * CIN) * 25;   // uniform -> s_load

    prefetch(0);
    float sum0 = 0.f, sum1 = 0.f;
    int buf = 0;

    for (int ci = 0; ci < CIN; ++ci) {
        float* xb = xs[buf];
        xb[lidx[0]] = pre[0];
        xb[lidx[1]] = pre[1];
        if (has3) xb[lidx[2]] = pre[2];
        __syncthreads();
        if (ci + 1 < CIN) prefetch(ci + 1);   // hides under compute

        const float* wp = wbase + ci * 25;    // uniform scalar loads
        float mx0 = -INFINITY, mx1 = -INFINITY;
        #pragma unroll
        for (int m = 0; m < 5; ++m) {
            const float2* rowp = reinterpret_cast<const float2*>(&xb[(ty + m) * XC + wc]);
            float2 a = rowp[0], c2 = rowp[1], e2 = rowp[2];
            float x0=a.x, x1=a.y, x2=c2.x, x3=c2.y, x4=e2.x, x5=e2.y;
            float w0_=wp[m*5+0], w1_=wp[m*5+1], w2_=wp[m*5+2], w3_=wp[m*5+3], w4_=wp[m*5+4];

            // out0: taps x0..x4 ; out1: taps x1..x5   (max3-shaped trees)
            float t0 = fmaxf(fmaxf(x0 + w0_, x1 + w1_), x2 + w2_);
            float u0 = fmaxf(x3 + w3_, x4 + w4_);
            mx0 = fmaxf(fmaxf(mx0, t0), u0);

            float t1 = fmaxf(fmaxf(x1 + w0_, x2 + w1_), x3 + w2_);
            float u1 = fmaxf(x4 + w3_, x5 + w4_);
            mx1 = fmaxf(fmaxf(mx1, t1), u1);
        }
        sum0 += mx0; sum1 += mx1;
        buf ^= 1;
    }

    const float bc = bias[co];
    float2 r; r.x = sum0 + bc; r.y = sum1 + bc;
    float* op = out + (((size_t)b * COUT + co) * HH + (h0 + ty)) * WW + w0 + wc;
    *reinterpret_cast<float2*>(op) = r;
}

extern "C" void kernel_launch(void* const* d_in, const int* in_sizes, int n_in,
                              void* d_out, int out_size, void* d_ws, size_t ws_size,
                              hipStream_t stream) {
    const float* x    = (const float*)d_in[0];
    const float* w    = (const float*)d_in[1];
    const float* bias = (const float*)d_in[2];
    float* out        = (float*)d_out;

    dim3 grid((HH / TH) * 2, COUT, BB);   // 10 x 32 x 4 = 1280 blocks
    semiconv_kernel<<<grid, NTHREADS, 0, stream>>>(x, w, bias, out);
}

// Round 5
// 42.634 us; speedup vs baseline: 1.1371x; 1.1371x over previous
//
#include <hip/hip_runtime.h>
#include <math.h>

#define CIN  32
#define COUT 32
#define BB   4
#define HH   80
#define WW   80
#define HW   (HH * WW)
#define NOUT (BB * COUT * HW)   // 819200
#define TH   16                 // output rows per block
#define XR   (TH + 4)           // 20 haloed rows
#define XC   (WW + 4)           // 84 haloed cols (stride keeps float4 align)
#define TILE (XR * XC)          // 1680
#define NT   320                // 16 rows x 20 col-groups (4 cols each)

// Each block: one 16x80 stripe, one co-PAIR (x LDS reads amortized over 2 co),
// one ci-chunk of CIN/NPARTS. Weights via uniform scalar loads (SGPR), issued
// before the barrier so the mandatory barrier drain hides SMEM latency.
template<int NPARTS>
__global__ __launch_bounds__(NT, 4) void semiconv_kernel(
    const float* __restrict__ x,     // [B, CIN, H, W]
    const float* __restrict__ w,     // [COUT, CIN, 5, 5]
    const float* __restrict__ bias,  // [COUT]
    float* __restrict__ dst)         // out (NPARTS==1) or partials [NPARTS][NOUT]
{
    constexpr int CIP = CIN / NPARTS;
    __shared__ __align__(16) float xs[2][TILE];

    const int tid = threadIdx.x;
    const int bh  = blockIdx.x;              // 0..4 row stripe
    const int cp  = blockIdx.y;              // 0..15 co-pair
    const int zz  = blockIdx.z;              // b * NPARTS + part
    const int b    = zz / NPARTS;
    const int part = zz % NPARTS;
    const int ci0  = part * CIP;
    const int h0   = bh * TH;
    const int co0  = cp * 2;

    const int ty = tid / 20;                 // 0..15
    const int tx = tid % 20;                 // 0..19
    const int wc = tx * 4;

    int goff[6];
    #pragma unroll
    for (int i = 0; i < 6; ++i) {
        int idx = tid + i * NT;
        int r = idx / XC, c = idx % XC;
        int gr = h0 + r - 2, gc = c - 2;
        goff[i] = (gr >= 0 && gr < HH && gc >= 0 && gc < WW) ? (gr * WW + gc) : -1;
    }
    const bool has6 = (tid < TILE - 5 * NT);   // tid < 80

    float pre[6];
    auto prefetch = [&](int ci) {
        const float* xp = x + (size_t)(b * CIN + ci) * HW;
        #pragma unroll
        for (int i = 0; i < 5; ++i)
            pre[i] = (goff[i] >= 0) ? xp[goff[i]] : -INFINITY;
        if (has6) pre[5] = (goff[5] >= 0) ? xp[goff[5]] : -INFINITY;
    };

    const float* wp0 = w + ((size_t)(co0    ) * CIN + ci0) * 25;  // uniform
    const float* wp1 = w + ((size_t)(co0 + 1) * CIN + ci0) * 25;  // uniform

    prefetch(ci0);
    float s0a=0.f,s1a=0.f,s2a=0.f,s3a=0.f;
    float s0b=0.f,s1b=0.f,s2b=0.f,s3b=0.f;
    int buf = 0;

    for (int k = 0; k < CIP; ++k) {
        // uniform scalar weight loads — latency hidden by the barrier below
        float w0[25], w1[25];
        #pragma unroll
        for (int j = 0; j < 25; ++j) { w0[j] = wp0[k * 25 + j]; w1[j] = wp1[k * 25 + j]; }

        float* xb = xs[buf];
        #pragma unroll
        for (int i = 0; i < 5; ++i) xb[tid + i * NT] = pre[i];
        if (has6) xb[tid + 5 * NT] = pre[5];
        __syncthreads();
        if (k + 1 < CIP) prefetch(ci0 + k + 1);   // hides under compute

        float a0=-INFINITY,a1=-INFINITY,a2=-INFINITY,a3=-INFINITY;
        float b0=-INFINITY,b1=-INFINITY,b2=-INFINITY,b3=-INFINITY;
        #pragma unroll
        for (int m = 0; m < 5; ++m) {
            const float4* rp = reinterpret_cast<const float4*>(&xb[(ty + m) * XC + wc]);
            float4 A = rp[0], C = rp[1];
            float x0=A.x,x1=A.y,x2=A.z,x3=A.w,x4=C.x,x5=C.y,x6=C.z,x7=C.w;
            {
                float q0=w0[5*m],q1=w0[5*m+1],q2=w0[5*m+2],q3=w0[5*m+3],q4=w0[5*m+4];
                float t, u;
                t=fmaxf(fmaxf(x0+q0,x1+q1),x2+q2); u=fmaxf(x3+q3,x4+q4); a0=fmaxf(fmaxf(a0,t),u);
                t=fmaxf(fmaxf(x1+q0,x2+q1),x3+q2); u=fmaxf(x4+q3,x5+q4); a1=fmaxf(fmaxf(a1,t),u);
                t=fmaxf(fmaxf(x2+q0,x3+q1),x4+q2); u=fmaxf(x5+q3,x6+q4); a2=fmaxf(fmaxf(a2,t),u);
                t=fmaxf(fmaxf(x3+q0,x4+q1),x5+q2); u=fmaxf(x6+q3,x7+q4); a3=fmaxf(fmaxf(a3,t),u);
            }
            {
                float q0=w1[5*m],q1=w1[5*m+1],q2=w1[5*m+2],q3=w1[5*m+3],q4=w1[5*m+4];
                float t, u;
                t=fmaxf(fmaxf(x0+q0,x1+q1),x2+q2); u=fmaxf(x3+q3,x4+q4); b0=fmaxf(fmaxf(b0,t),u);
                t=fmaxf(fmaxf(x1+q0,x2+q1),x3+q2); u=fmaxf(x4+q3,x5+q4); b1=fmaxf(fmaxf(b1,t),u);
                t=fmaxf(fmaxf(x2+q0,x3+q1),x4+q2); u=fmaxf(x5+q3,x6+q4); b2=fmaxf(fmaxf(b2,t),u);
                t=fmaxf(fmaxf(x3+q0,x4+q1),x5+q2); u=fmaxf(x6+q3,x7+q4); b3=fmaxf(fmaxf(b3,t),u);
            }
        }
        s0a+=a0; s1a+=a1; s2a+=a2; s3a+=a3;
        s0b+=b0; s1b+=b1; s2b+=b2; s3b+=b3;
        buf ^= 1;
    }

    size_t oiA = (((size_t)b * COUT + co0    ) * HH + (h0 + ty)) * WW + wc;
    size_t oiB = (((size_t)b * COUT + co0 + 1) * HH + (h0 + ty)) * WW + wc;
    float4 rA, rB;
    if (NPARTS == 1) {
        const float bcA = bias[co0], bcB = bias[co0 + 1];
        rA.x=s0a+bcA; rA.y=s1a+bcA; rA.z=s2a+bcA; rA.w=s3a+bcA;
        rB.x=s0b+bcB; rB.y=s1b+bcB; rB.z=s2b+bcB; rB.w=s3b+bcB;
    } else {
        rA.x=s0a; rA.y=s1a; rA.z=s2a; rA.w=s3a;
        rB.x=s0b; rB.y=s1b; rB.z=s2b; rB.w=s3b;
        oiA += (size_t)part * NOUT;
        oiB += (size_t)part * NOUT;
    }
    *reinterpret_cast<float4*>(dst + oiA) = rA;
    *reinterpret_cast<float4*>(dst + oiB) = rB;
}

template<int NPARTS>
__global__ __launch_bounds__(256) void reduceN_kernel(
    const float* __restrict__ ws, const float* __restrict__ bias,
    float* __restrict__ out)
{
    int i4 = blockIdx.x * 256 + threadIdx.x;        // 0..204799
    const float4* p = reinterpret_cast<const float4*>(ws);
    float4 r = p[i4];
    #pragma unroll
    for (int q = 1; q < NPARTS; ++q) {
        float4 t = p[i4 + (size_t)q * (NOUT / 4)];
        r.x += t.x; r.y += t.y; r.z += t.z; r.w += t.w;
    }
    int co = (i4 / (HW / 4)) & (COUT - 1);
    float bc = bias[co];
    r.x += bc; r.y += bc; r.z += bc; r.w += bc;
    reinterpret_cast<float4*>(out)[i4] = r;
}

extern "C" void kernel_launch(void* const* d_in, const int* in_sizes, int n_in,
                              void* d_out, int out_size, void* d_ws, size_t ws_size,
                              hipStream_t stream) {
    const float* x    = (const float*)d_in[0];
    const float* w    = (const float*)d_in[1];
    const float* bias = (const float*)d_in[2];
    float* out        = (float*)d_out;

    const size_t need4 = 4ull * NOUT * sizeof(float);  // 13.1 MB
    const size_t need2 = 2ull * NOUT * sizeof(float);  // 6.55 MB

    if (ws_size >= need4) {
        dim3 grid(HH / TH, COUT / 2, BB * 4);          // 5 x 16 x 16 = 1280 blocks
        semiconv_kernel<4><<<grid, NT, 0, stream>>>(x, w, bias, (float*)d_ws);
        reduceN_kernel<4><<<NOUT / 4 / 256, 256, 0, stream>>>((const float*)d_ws, bias, out);
    } else if (ws_size >= need2) {
        dim3 grid(HH / TH, COUT / 2, BB * 2);          // 640 blocks
        semiconv_kernel<2><<<grid, NT, 0, stream>>>(x, w, bias, (float*)d_ws);
        reduceN_kernel<2><<<NOUT / 4 / 256, 256, 0, stream>>>((const float*)d_ws, bias, out);
    } else {
        dim3 grid(HH / TH, COUT / 2, BB);              // 320 blocks fallback
        semiconv_kernel<1><<<grid, NT, 0, stream>>>(x, w, bias, out);
    }
}

// Round 6
// 38.193 us; speedup vs baseline: 1.2693x; 1.1163x over previous
//
#include <hip/hip_runtime.h>
#include <math.h>

#define CIN  32
#define COUT 32
#define BB   4
#define HH   80
#define WW   80
#define HW   (HH * WW)
#define NOUT (BB * COUT * HW)   // 819200
#define TH   16                 // output rows per block
#define XR   20                 // haloed rows
#define XC   84                 // haloed cols (16B-aligned rows: 84*4=336)
#define TILE 1680
#define NT   320                // 16 rows x 20 col-groups (4 cols each)

typedef float v4f __attribute__((ext_vector_type(4)));

__device__ __forceinline__ float max3f(float a, float b, float c) {
    float d;
    asm("v_max3_f32 %0, %1, %2, %3" : "=v"(d) : "v"(a), "v"(b), "v"(c));
    return d;
}

__device__ __forceinline__ void load_lds4(const float* g, float* l) {
    __builtin_amdgcn_global_load_lds(
        (const __attribute__((address_space(1))) void*)g,
        (__attribute__((address_space(3))) void*)l, 4, 0, 0);
}

// One block: 16x80 stripe, co-PAIR (x amortized over 2 co), ci-chunk of CIN/NP.
// x staged via global_load_lds (lane-linear dest, OOB cells pre-filled -inf once).
// Weights in LDS, (co0,co1)-interleaved, 12-float padded rows -> broadcast b128.
template<int NP>
__global__ __launch_bounds__(NT, 7) void semiconv_kernel(
    const float* __restrict__ x,     // [B, CIN, H, W]
    const float* __restrict__ w,     // [COUT, CIN, 5, 5]
    const float* __restrict__ bias,  // [COUT]
    float* __restrict__ dst)         // out (NP==1) or partials [NP][NOUT]
{
    constexpr int CP = CIN / NP;
    __shared__ __align__(16) float xs0[TILE];
    __shared__ __align__(16) float xs1[TILE];
    __shared__ __align__(16) float wl[CP * 60];   // [k][m][12]: pairs (w0,w1) n=0..4 + 2 pad

    const int tid = threadIdx.x;
    const int bh  = blockIdx.x;               // 0..4 row stripe
    const int cp  = blockIdx.y;               // 0..15 co-pair
    const int zz  = blockIdx.z;               // b * NP + part
    const int b    = zz / NP;
    const int part = zz % NP;
    const int ci0  = part * CP;
    const int h0   = bh * TH;
    const int co0  = cp * 2;

    // ---- stage interleaved weights ----
    for (int idx = tid; idx < CP * 60; idx += NT) {
        int k = idx / 60, r = idx % 60, m = r / 12, q = r % 12;
        float v = 0.f;
        if (q < 10)
            v = w[((size_t)(co0 + (q & 1)) * CIN + ci0 + k) * 25 + m * 5 + (q >> 1)];
        wl[idx] = v;
    }

    const int ty = tid / 20, tx = tid % 20, wc = tx * 4;

    // ---- per-chunk offsets; -inf prefill of ci-invariant OOB cells (both buffers) ----
    int goff[6];
    #pragma unroll
    for (int i = 0; i < 6; ++i) {
        int idx = tid + i * NT;
        int r = idx / XC, c = idx % XC;
        int gr = h0 + r - 2, gc = c - 2;
        bool in = (idx < TILE) && gr >= 0 && gr < HH && gc >= 0 && gc < WW;
        goff[i] = in ? (gr * WW + gc) : -1;
        if (idx < TILE && !in) { xs0[idx] = -INFINITY; xs1[idx] = -INFINITY; }
    }

    const float* xbase = x + (size_t)(b * CIN + ci0) * HW;
    const int wave64 = tid & ~63;

    // ---- stage tile k=0 into xs0 (direct global->LDS DMA) ----
    #pragma unroll
    for (int i = 0; i < 6; ++i)
        if (goff[i] >= 0) load_lds4(xbase + goff[i], xs0 + i * NT + wave64);

    const float* xnext = xbase + HW;
    float sA[4] = {0.f, 0.f, 0.f, 0.f}, sB[4] = {0.f, 0.f, 0.f, 0.f};
    const int xro = ty * XC + wc;

    __syncthreads();   // weights + -inf prefill + tile 0 all complete

    auto step = [&](int k, const float* xrd, float* xwr) {
        if (k + 1 < CP) {                       // prefetch next tile, hidden under compute
            #pragma unroll
            for (int i = 0; i < 6; ++i)
                if (goff[i] >= 0) load_lds4(xnext + goff[i], xwr + i * NT + wave64);
            xnext += HW;
        }
        const float* wk = &wl[k * 60];
        float aA[4] = {-INFINITY, -INFINITY, -INFINITY, -INFINITY};
        float aB[4] = {-INFINITY, -INFINITY, -INFINITY, -INFINITY};
        #pragma unroll
        for (int m = 0; m < 5; ++m) {
            v4f A  = *(const v4f*)(xrd + xro + m * XC);
            v4f C  = *(const v4f*)(xrd + xro + m * XC + 4);
            v4f W0 = *(const v4f*)(wk + m * 12);
            v4f W1 = *(const v4f*)(wk + m * 12 + 4);
            v4f W2 = *(const v4f*)(wk + m * 12 + 8);
            float xr[8] = {A.x, A.y, A.z, A.w, C.x, C.y, C.z, C.w};
            float wa[5] = {W0.x, W0.z, W1.x, W1.z, W2.x};
            float wb[5] = {W0.y, W0.w, W1.y, W1.w, W2.y};
            #pragma unroll
            for (int j = 0; j < 4; ++j) {
                float p0 = xr[j] + wa[0], p1 = xr[j+1] + wa[1], p2 = xr[j+2] + wa[2];
                float p3 = xr[j+3] + wa[3], p4 = xr[j+4] + wa[4];
                aA[j] = max3f(aA[j], max3f(p0, p1, p2), fmaxf(p3, p4));
                p0 = xr[j] + wb[0]; p1 = xr[j+1] + wb[1]; p2 = xr[j+2] + wb[2];
                p3 = xr[j+3] + wb[3]; p4 = xr[j+4] + wb[4];
                aB[j] = max3f(aB[j], max3f(p0, p1, p2), fmaxf(p3, p4));
            }
        }
        #pragma unroll
        for (int j = 0; j < 4; ++j) { sA[j] += aA[j]; sB[j] += aB[j]; }
        __syncthreads();   // drains vmcnt (next tile landed) + lgkmcnt (reads done)
    };

    #pragma unroll 1
    for (int k = 0; k < CP; k += 2) {   // CP is even for NP in {1,2,4}
        step(k,     xs0, xs1);
        step(k + 1, xs1, xs0);
    }

    size_t oiA = (((size_t)b * COUT + co0) * HH + (h0 + ty)) * WW + wc;
    size_t oiB = oiA + (size_t)HW;      // co0+1
    v4f rA = {sA[0], sA[1], sA[2], sA[3]};
    v4f rB = {sB[0], sB[1], sB[2], sB[3]};
    float* o = dst;
    if (NP == 1) {
        float bcA = bias[co0], bcB = bias[co0 + 1];
        rA.x += bcA; rA.y += bcA; rA.z += bcA; rA.w += bcA;
        rB.x += bcB; rB.y += bcB; rB.z += bcB; rB.w += bcB;
    } else {
        o += (size_t)part * NOUT;
    }
    *(v4f*)(o + oiA) = rA;
    *(v4f*)(o + oiB) = rB;
}

template<int NP>
__global__ __launch_bounds__(256) void reduceN_kernel(
    const float* __restrict__ ws, const float* __restrict__ bias,
    float* __restrict__ out)
{
    int i4 = blockIdx.x * 256 + threadIdx.x;        // 0..204799
    const float4* p = reinterpret_cast<const float4*>(ws);
    float4 r = p[i4];
    #pragma unroll
    for (int q = 1; q < NP; ++q) {
        float4 t = p[i4 + (size_t)q * (NOUT / 4)];
        r.x += t.x; r.y += t.y; r.z += t.z; r.w += t.w;
    }
    int co = (i4 / (HW / 4)) & (COUT - 1);
    float bc = bias[co];
    r.x += bc; r.y += bc; r.z += bc; r.w += bc;
    reinterpret_cast<float4*>(out)[i4] = r;
}

extern "C" void kernel_launch(void* const* d_in, const int* in_sizes, int n_in,
                              void* d_out, int out_size, void* d_ws, size_t ws_size,
                              hipStream_t stream) {
    const float* x    = (const float*)d_in[0];
    const float* w    = (const float*)d_in[1];
    const float* bias = (const float*)d_in[2];
    float* out        = (float*)d_out;

    const size_t need4 = 4ull * NOUT * sizeof(float);  // 13.1 MB
    const size_t need2 = 2ull * NOUT * sizeof(float);  // 6.55 MB

    if (ws_size >= need4) {
        dim3 grid(HH / TH, COUT / 2, BB * 4);          // 5 x 16 x 16 = 1280 blocks
        semiconv_kernel<4><<<grid, NT, 0, stream>>>(x, w, bias, (float*)d_ws);
        reduceN_kernel<4><<<NOUT / 4 / 256, 256, 0, stream>>>((const float*)d_ws, bias, out);
    } else if (ws_size >= need2) {
        dim3 grid(HH / TH, COUT / 2, BB * 2);          // 640 blocks
        semiconv_kernel<2><<<grid, NT, 0, stream>>>(x, w, bias, (float*)d_ws);
        reduceN_kernel<2><<<NOUT / 4 / 256, 256, 0, stream>>>((const float*)d_ws, bias, out);
    } else {
        dim3 grid(HH / TH, COUT / 2, BB);              // 320 blocks fallback
        semiconv_kernel<1><<<grid, NT, 0, stream>>>(x, w, bias, out);
    }
}

// Round 7
// 38.193 us; speedup vs baseline: 1.2693x; 1.0000x over previous
//
#include <hip/hip_runtime.h>
#include <math.h>

#define CIN  32
#define COUT 32
#define BB   4
#define HH   80
#define WW   80
#define HW   (HH * WW)
#define NOUT (BB * COUT * HW)   // 819200
#define TH   16                 // output rows per block
#define XR   20                 // haloed rows
#define XC   88                 // haloed cols, padded: stride 88 dw == 24 mod 32 banks
#define TILE (XR * XC)          // 1760
#define NT   320                // 16 rows x 20 col-groups (4 cols each)

typedef float v4f __attribute__((ext_vector_type(4)));

__device__ __forceinline__ float max3f(float a, float b, float c) {
    float d;
    asm("v_max3_f32 %0, %1, %2, %3" : "=v"(d) : "v"(a), "v"(b), "v"(c));
    return d;
}

__device__ __forceinline__ void load_lds4(const float* g, float* l) {
    __builtin_amdgcn_global_load_lds(
        (const __attribute__((address_space(1))) void*)g,
        (__attribute__((address_space(3))) void*)l, 4, 0, 0);
}

// One block: 16x80 stripe, co-PAIR (x LDS reads amortized over 2 co), ci-chunk
// of CIN/NP. x staged via global_load_lds (lane-linear dest; OOB cells
// prefilled -inf once). Weights: coalesced global read (two contiguous
// 200-float runs) scattered once into interleaved LDS layout [k][m][12].
template<int NP>
__global__ __launch_bounds__(NT, 6) void semiconv_kernel(
    const float* __restrict__ x,     // [B, CIN, H, W]
    const float* __restrict__ w,     // [COUT, CIN, 5, 5]
    const float* __restrict__ bias,  // [COUT]
    float* __restrict__ dst)         // out (NP==1) or partials [NP][NOUT]
{
    constexpr int CP = CIN / NP;
    __shared__ __align__(16) float xs0[TILE];
    __shared__ __align__(16) float xs1[TILE];
    __shared__ __align__(16) float wl[CP * 60];   // [k][m][12]: (co0,co1) pairs n=0..4 + 2 pad

    const int tid = threadIdx.x;
    const int bh  = blockIdx.x;               // 0..4 row stripe
    const int cp  = blockIdx.y;               // 0..15 co-pair
    const int zz  = blockIdx.z;               // b * NP + part
    const int b    = zz / NP;
    const int part = zz % NP;
    const int ci0  = part * CP;
    const int h0   = bh * TH;
    const int co0  = cp * 2;

    // ---- coalesced weight staging: two contiguous 200-float runs ----
    for (int idx = tid; idx < CP * 50; idx += NT) {
        int run = idx / (CP * 25);            // which co of the pair
        int r   = idx % (CP * 25);            // flat within (ci-chunk, 25 taps)
        int k = r / 25, t = r % 25, m = t / 5, n = t % 5;
        float v = w[((size_t)(co0 + run) * CIN + ci0) * 25 + r];  // contiguous in r
        wl[k * 60 + m * 12 + n * 2 + run] = v;
    }

    const int ty = tid / 20, tx = tid % 20, wc = tx * 4;

    // ---- per-chunk offsets; -inf prefill of ci-invariant OOB/pad cells ----
    int goff[6];
    #pragma unroll
    for (int i = 0; i < 6; ++i) {
        int idx = tid + i * NT;
        int r = idx / XC, c = idx % XC;
        int gr = h0 + r - 2, gc = c - 2;
        bool in = (idx < TILE) && gr >= 0 && gr < HH && gc >= 0 && gc < WW;
        goff[i] = in ? (gr * WW + gc) : -1;
        if (idx < TILE && !in) { xs0[idx] = -INFINITY; xs1[idx] = -INFINITY; }
    }
    const bool has6 = (tid < TILE - 5 * NT);   // tid < 160

    const float* xbase = x + (size_t)(b * CIN + ci0) * HW;
    const int wave64 = tid & ~63;

    // ---- stage tile k=0 into xs0 ----
    #pragma unroll
    for (int i = 0; i < 5; ++i)
        if (goff[i] >= 0) load_lds4(xbase + goff[i], xs0 + i * NT + wave64);
    if (has6 && goff[5] >= 0) load_lds4(xbase + goff[5], xs0 + 5 * NT + wave64);

    const float* xnext = xbase + HW;
    float sA[4] = {0.f, 0.f, 0.f, 0.f}, sB[4] = {0.f, 0.f, 0.f, 0.f};
    const int xro = ty * XC + wc;

    __syncthreads();   // weights + -inf prefill + tile 0 complete

    auto step = [&](int k, const float* xrd, float* xwr) {
        if (k + 1 < CP) {                     // prefetch next tile under compute
            #pragma unroll
            for (int i = 0; i < 5; ++i)
                if (goff[i] >= 0) load_lds4(xnext + goff[i], xwr + i * NT + wave64);
            if (has6 && goff[5] >= 0) load_lds4(xnext + goff[5], xwr + 5 * NT + wave64);
            xnext += HW;
        }
        const float* wk = &wl[k * 60];
        float aA[4] = {-INFINITY, -INFINITY, -INFINITY, -INFINITY};
        float aB[4] = {-INFINITY, -INFINITY, -INFINITY, -INFINITY};
        #pragma unroll
        for (int m = 0; m < 5; ++m) {
            v4f A  = *(const v4f*)(xrd + xro + m * XC);
            v4f C  = *(const v4f*)(xrd + xro + m * XC + 4);
            v4f W0 = *(const v4f*)(wk + m * 12);
            v4f W1 = *(const v4f*)(wk + m * 12 + 4);
            v4f W2 = *(const v4f*)(wk + m * 12 + 8);
            float xr[8] = {A.x, A.y, A.z, A.w, C.x, C.y, C.z, C.w};
            float wa[5] = {W0.x, W0.z, W1.x, W1.z, W2.x};
            float wb[5] = {W0.y, W0.w, W1.y, W1.w, W2.y};
            #pragma unroll
            for (int j = 0; j < 4; ++j) {
                float p0 = xr[j] + wa[0], p1 = xr[j+1] + wa[1], p2 = xr[j+2] + wa[2];
                float p3 = xr[j+3] + wa[3], p4 = xr[j+4] + wa[4];
                aA[j] = max3f(aA[j], max3f(p0, p1, p2), fmaxf(p3, p4));
                p0 = xr[j] + wb[0]; p1 = xr[j+1] + wb[1]; p2 = xr[j+2] + wb[2];
                p3 = xr[j+3] + wb[3]; p4 = xr[j+4] + wb[4];
                aB[j] = max3f(aB[j], max3f(p0, p1, p2), fmaxf(p3, p4));
            }
        }
        #pragma unroll
        for (int j = 0; j < 4; ++j) { sA[j] += aA[j]; sB[j] += aB[j]; }
        __syncthreads();   // next tile landed + all reads of xrd done
    };

    #pragma unroll 1
    for (int k = 0; k < CP; k += 2) {
        step(k,     xs0, xs1);
        step(k + 1, xs1, xs0);
    }

    size_t oiA = (((size_t)b * COUT + co0) * HH + (h0 + ty)) * WW + wc;
    size_t oiB = oiA + (size_t)HW;            // co0+1
    v4f rA = {sA[0], sA[1], sA[2], sA[3]};
    v4f rB = {sB[0], sB[1], sB[2], sB[3]};
    float* o = dst;
    if (NP == 1) {
        float bcA = bias[co0], bcB = bias[co0 + 1];
        rA.x += bcA; rA.y += bcA; rA.z += bcA; rA.w += bcA;
        rB.x += bcB; rB.y += bcB; rB.z += bcB; rB.w += bcB;
    } else {
        o += (size_t)part * NOUT;
    }
    *(v4f*)(o + oiA) = rA;
    *(v4f*)(o + oiB) = rB;
}

template<int NP>
__global__ __launch_bounds__(256) void reduceN_kernel(
    const float* __restrict__ ws, const float* __restrict__ bias,
    float* __restrict__ out)
{
    int i4 = blockIdx.x * 256 + threadIdx.x;        // 0..204799
    const float4* p = reinterpret_cast<const float4*>(ws);
    float4 r = p[i4];
    #pragma unroll
    for (int q = 1; q < NP; ++q) {
        float4 t = p[i4 + (size_t)q * (NOUT / 4)];
        r.x += t.x; r.y += t.y; r.z += t.z; r.w += t.w;
    }
    int co = (i4 / (HW / 4)) & (COUT - 1);
    float bc = bias[co];
    r.x += bc; r.y += bc; r.z += bc; r.w += bc;
    reinterpret_cast<float4*>(out)[i4] = r;
}

extern "C" void kernel_launch(void* const* d_in, const int* in_sizes, int n_in,
                              void* d_out, int out_size, void* d_ws, size_t ws_size,
                              hipStream_t stream) {
    const float* x    = (const float*)d_in[0];
    const float* w    = (const float*)d_in[1];
    const float* bias = (const float*)d_in[2];
    float* out        = (float*)d_out;

    const size_t need4 = 4ull * NOUT * sizeof(float);  // 13.1 MB
    const size_t need2 = 2ull * NOUT * sizeof(float);  // 6.55 MB

    if (ws_size >= need4) {
        dim3 grid(HH / TH, COUT / 2, BB * 4);          // 5 x 16 x 16 = 1280 blocks
        semiconv_kernel<4><<<grid, NT, 0, stream>>>(x, w, bias, (float*)d_ws);
        reduceN_kernel<4><<<NOUT / 4 / 256, 256, 0, stream>>>((const float*)d_ws, bias, out);
    } else if (ws_size >= need2) {
        dim3 grid(HH / TH, COUT / 2, BB * 2);          // 640 blocks
        semiconv_kernel<2><<<grid, NT, 0, stream>>>(x, w, bias, (float*)d_ws);
        reduceN_kernel<2><<<NOUT / 4 / 256, 256, 0, stream>>>((const float*)d_ws, bias, out);
    } else {
        dim3 grid(HH / TH, COUT / 2, BB);              // 320 blocks fallback
        semiconv_kernel<1><<<grid, NT, 0, stream>>>(x, w, bias, out);
    }
}